// Round 4
// baseline (103.114 us; speedup 1.0000x reference)
//
#include <hip/hip_runtime.h>

// QSP via Laurent polynomial, ONE kernel again (R14).
// u00(theta) = sum_{t=0..127} gamma_t e^{i(2t-127)theta}; gamma from phis.
// R13 showed the split main kernel drops under 42us but a second graph-node
// launch + serialized 1-wave gamma dispatch ate the win (dur 86.5 -> 89.2).
// R14: gamma recurrence is WAVE-LOCAL (64 lanes hold 128 slots, only
// cross-lane op is DPP shr1) -> EVERY wave computes gamma redundantly
// in-register. No LDS, no __syncthreads, no second launch. The Horner loop
// broadcasts gamma_t via v_readlane (uniform SGPR index) straight into the
// FMA src2 slot; h_k = 0.5 e^{i phi_k} likewise lives in lane k's registers
// and is broadcast by readlane during the recurrence.
// Floor: 2^21 elems * 128 steps * 8 flops = 2.15 GFLOP @ 157 TF = 13.7 us.

__device__ __forceinline__ float wave_shr1(float x) {
    // lane L <- lane L-1, lane 0 <- 0 (DPP wave_shr:1, bound_ctrl=1)
    return __builtin_bit_cast(float,
        __builtin_amdgcn_update_dpp(0, __builtin_bit_cast(int, x),
                                    0x138, 0xf, 0xf, true));
}

__device__ __forceinline__ float rlane(float x, int l) {
    // broadcast lane l's value to all lanes (l must be wave-uniform)
    return __builtin_bit_cast(float,
        __builtin_amdgcn_readlane(__builtin_bit_cast(int, x), l));
}

__global__ __launch_bounds__(256, 4) void qsp_fused(
    const float* __restrict__ th,
    const float* __restrict__ phis,
    float* __restrict__ out,    // [0,B): real, [B,2B): imag
    int Bq8)                     // B/8
{
    const int tid  = threadIdx.x;
    const int lane = tid & 63;
    const int idx  = blockIdx.x * blockDim.x + tid;
    const int lidx = (idx < Bq8) ? idx : 0;

    // issue theta loads first; their latency hides under the gamma recurrence
    const float4 ta = ((const float4*)th)[2 * lidx];
    const float4 tb = ((const float4*)th)[2 * lidx + 1];

    // ---- per-wave gamma setup: lane k holds h_k = 0.5 e^{i phi_k} ----------
    float sp, cp;
    __sincosf(phis[lane], &sp, &cp);
    const float hAx = 0.5f * cp, hAy = 0.5f * sp;        // k = lane
    __sincosf(phis[lane + 64], &sp, &cp);
    const float hBx = 0.5f * cp, hBy = 0.5f * sp;        // k = lane + 64

    // lane L holds slots j=2L (A0/B0), j=2L+1 (A1/B1), scalar re/im
    float A0r = 0.f, A0i = 0.f, B0r = 0.f, B0i = 0.f;
    float A1r = 0.f, A1i = 0.f, B1r = 0.f, B1i = 0.f;
    const float h0x = rlane(hAx, 0), h0y = rlane(hAy, 0);
    if (lane == 0) { A0r = 2.f * h0x; A0i = 2.f * h0y; } // A[0] = e_0

    // compressed recurrence (validated R6-R9):
    //   A'[j] = e_k  * 0.5*(A[j-1] + A[j] + B[j-1] - B[j])
    //   B'[j] = ek^* * 0.5*(A[j-1] - A[j] + B[j-1] + B[j])
    #define QSP_REC(hx_, hy_)                                                 \
    {                                                                         \
        const float hx = (hx_), hy = (hy_);                                   \
        const float pAr = wave_shr1(A1r), pAi = wave_shr1(A1i);               \
        const float pBr = wave_shr1(B1r), pBi = wave_shr1(B1i);               \
        const float u0r = pAr + pBr, u0i = pAi + pBi;                         \
        const float v0r = A0r - B0r, v0i = A0i - B0i;                         \
        const float sA0r = u0r + v0r, sA0i = u0i + v0i;                       \
        const float sB0r = u0r - v0r, sB0i = u0i - v0i;                       \
        const float u1r = A0r + B0r, u1i = A0i + B0i;                         \
        const float v1r = A1r - B1r, v1i = A1i - B1i;                         \
        const float sA1r = u1r + v1r, sA1i = u1i + v1i;                       \
        const float sB1r = u1r - v1r, sB1i = u1i - v1i;                       \
        A0r = fmaf(hx, sA0r, -hy * sA0i);                                     \
        A0i = fmaf(hx, sA0i,  hy * sA0r);                                     \
        B0r = fmaf(hx, sB0r,  hy * sB0i);                                     \
        B0i = fmaf(hx, sB0i, -hy * sB0r);                                     \
        A1r = fmaf(hx, sA1r, -hy * sA1i);                                     \
        A1i = fmaf(hx, sA1i,  hy * sA1r);                                     \
        B1r = fmaf(hx, sB1r,  hy * sB1i);                                     \
        B1i = fmaf(hx, sB1i, -hy * sB1r);                                     \
    }

    #pragma unroll 4
    for (int k = 1; k < 64; ++k)   QSP_REC(rlane(hAx, k), rlane(hAy, k))
    #pragma unroll 4
    for (int k = 0; k < 64; ++k)   QSP_REC(rlane(hBx, k), rlane(hBy, k))
    #undef QSP_REC
    // lane L now holds gamma_{2L} = (A0r,A0i), gamma_{2L+1} = (A1r,A1i)

    // ---- per-thread prologue: z = e^{2 i theta} ----------------------------
    const float th8[8] = {ta.x, ta.y, ta.z, ta.w, tb.x, tb.y, tb.z, tb.w};
    float zr[8], zi[8];
    #pragma unroll
    for (int e = 0; e < 8; ++e) {
        float s, c;
        __sincosf(2.f * th8[e], &s, &c);
        zr[e] = c; zi[e] = s;
    }

    float ar[8], ai[8];
    #pragma unroll
    for (int e = 0; e < 8; ++e) { ar[e] = 0.f; ai[e] = 0.f; }

    // ---- Horner in z, t = 127..0; gamma broadcast via readlane -------------
    #define QSP_STEP(gr, gi)                                                  \
        _Pragma("unroll")                                                     \
        for (int e = 0; e < 8; ++e) {                                         \
            const float nr = fmaf(ar[e], zr[e], fmaf(-ai[e], zi[e], (gr)));   \
            const float ni = fmaf(ar[e], zi[e], fmaf( ai[e], zr[e], (gi)));   \
            ar[e] = nr; ai[e] = ni;                                           \
        }

    #pragma unroll 2
    for (int jj = 63; jj >= 0; --jj) {
        const float g1r = rlane(A1r, jj), g1i = rlane(A1i, jj);
        QSP_STEP(g1r, g1i)               // t = 2jj+1
        const float g0r = rlane(A0r, jj), g0i = rlane(A0i, jj);
        QSP_STEP(g0r, g0i)               // t = 2jj
    }
    #undef QSP_STEP

    // ---- multiply by e^{-127 i theta}: re = ar*C + ai*S, im = ai*C - ar*S --
    float orv[8], oiv[8];
    #pragma unroll
    for (int e = 0; e < 8; ++e) {
        float S, C;
        __sincosf(127.f * th8[e], &S, &C);
        orv[e] = fmaf(ar[e], C,  ai[e] * S);
        oiv[e] = fmaf(ai[e], C, -ar[e] * S);
    }

    if (idx < Bq8) {
        float4* o4 = (float4*)out;
        const int ib = 2 * Bq8;   // imag base in float4 units (= B/4)
        o4[2 * idx]          = make_float4(orv[0], orv[1], orv[2], orv[3]);
        o4[2 * idx + 1]      = make_float4(orv[4], orv[5], orv[6], orv[7]);
        o4[ib + 2 * idx]     = make_float4(oiv[0], oiv[1], oiv[2], oiv[3]);
        o4[ib + 2 * idx + 1] = make_float4(oiv[4], oiv[5], oiv[6], oiv[7]);
    }
}

extern "C" void kernel_launch(void* const* d_in, const int* in_sizes, int n_in,
                              void* d_out, int out_size, void* d_ws, size_t ws_size,
                              hipStream_t stream)
{
    const float* th   = (const float*)d_in[0];
    const float* phis = (const float*)d_in[1];
    float* out = (float*)d_out;
    const int B = in_sizes[0];          // 2097152
    const int Bq8 = B >> 3;             // 262144 threads
    const int block = 256;              // 4 waves
    const int grid = (Bq8 + block - 1) / block;   // 1024 blocks = 4/CU, 16 waves/CU
    qsp_fused<<<grid, block, 0, stream>>>(th, phis, out, Bq8);
}

// Round 5
// 95.253 us; speedup vs baseline: 1.0825x; 1.0825x over previous
//
#include <hip/hip_runtime.h>

// QSP via Laurent polynomial, one kernel (R15).
// u00(theta) = sum_{t=0..127} gamma_t e^{i(2t-127)theta}; gamma from phis.
// R14 measured: readlane-broadcast structure is issue-bound (VALUBusy 69%,
// kernel 53us) but per-wave redundant gamma = 15.2us of 30us issue work.
// R15: HALVE the wave count (grid 512, 16 elems/thread). Horner issue is
// constant; gamma redundancy halves (15.2 -> 7.6us). Horner has 32 indep
// FMA chains so 2 waves/SIMD still saturates issue. VGPR ~110 fits
// __launch_bounds__(256,2). Everything else identical to the passing R14.

__device__ __forceinline__ float wave_shr1(float x) {
    // lane L <- lane L-1, lane 0 <- 0 (DPP wave_shr:1, bound_ctrl=1)
    return __builtin_bit_cast(float,
        __builtin_amdgcn_update_dpp(0, __builtin_bit_cast(int, x),
                                    0x138, 0xf, 0xf, true));
}

__device__ __forceinline__ float rlane(float x, int l) {
    // broadcast lane l's value to all lanes (l must be wave-uniform)
    return __builtin_bit_cast(float,
        __builtin_amdgcn_readlane(__builtin_bit_cast(int, x), l));
}

__global__ __launch_bounds__(256, 2) void qsp_fused(
    const float* __restrict__ th,
    const float* __restrict__ phis,
    float* __restrict__ out,    // [0,B): real, [B,2B): imag
    int Bq16)                    // B/16
{
    const int tid  = threadIdx.x;
    const int lane = tid & 63;
    const int idx  = blockIdx.x * blockDim.x + tid;
    const int lidx = (idx < Bq16) ? idx : 0;

    // issue theta loads first; latency hides under the gamma recurrence
    const float4 t0 = ((const float4*)th)[4 * lidx];
    const float4 t1 = ((const float4*)th)[4 * lidx + 1];
    const float4 t2 = ((const float4*)th)[4 * lidx + 2];
    const float4 t3 = ((const float4*)th)[4 * lidx + 3];

    // ---- per-wave gamma setup: lane k holds h_k = 0.5 e^{i phi_k} ----------
    float sp, cp;
    __sincosf(phis[lane], &sp, &cp);
    const float hAx = 0.5f * cp, hAy = 0.5f * sp;        // k = lane
    __sincosf(phis[lane + 64], &sp, &cp);
    const float hBx = 0.5f * cp, hBy = 0.5f * sp;        // k = lane + 64

    // lane L holds slots j=2L (A0/B0), j=2L+1 (A1/B1), scalar re/im
    float A0r = 0.f, A0i = 0.f, B0r = 0.f, B0i = 0.f;
    float A1r = 0.f, A1i = 0.f, B1r = 0.f, B1i = 0.f;
    const float h0x = rlane(hAx, 0), h0y = rlane(hAy, 0);
    if (lane == 0) { A0r = 2.f * h0x; A0i = 2.f * h0y; } // A[0] = e_0

    // compressed recurrence (validated R6-R9):
    //   A'[j] = e_k  * 0.5*(A[j-1] + A[j] + B[j-1] - B[j])
    //   B'[j] = ek^* * 0.5*(A[j-1] - A[j] + B[j-1] + B[j])
    #define QSP_REC(hx_, hy_)                                                 \
    {                                                                         \
        const float hx = (hx_), hy = (hy_);                                   \
        const float pAr = wave_shr1(A1r), pAi = wave_shr1(A1i);               \
        const float pBr = wave_shr1(B1r), pBi = wave_shr1(B1i);               \
        const float u0r = pAr + pBr, u0i = pAi + pBi;                         \
        const float v0r = A0r - B0r, v0i = A0i - B0i;                         \
        const float sA0r = u0r + v0r, sA0i = u0i + v0i;                       \
        const float sB0r = u0r - v0r, sB0i = u0i - v0i;                       \
        const float u1r = A0r + B0r, u1i = A0i + B0i;                         \
        const float v1r = A1r - B1r, v1i = A1i - B1i;                         \
        const float sA1r = u1r + v1r, sA1i = u1i + v1i;                       \
        const float sB1r = u1r - v1r, sB1i = u1i - v1i;                       \
        A0r = fmaf(hx, sA0r, -hy * sA0i);                                     \
        A0i = fmaf(hx, sA0i,  hy * sA0r);                                     \
        B0r = fmaf(hx, sB0r,  hy * sB0i);                                     \
        B0i = fmaf(hx, sB0i, -hy * sB0r);                                     \
        A1r = fmaf(hx, sA1r, -hy * sA1i);                                     \
        A1i = fmaf(hx, sA1i,  hy * sA1r);                                     \
        B1r = fmaf(hx, sB1r,  hy * sB1i);                                     \
        B1i = fmaf(hx, sB1i, -hy * sB1r);                                     \
    }

    #pragma unroll 4
    for (int k = 1; k < 64; ++k)   QSP_REC(rlane(hAx, k), rlane(hAy, k))
    #pragma unroll 4
    for (int k = 0; k < 64; ++k)   QSP_REC(rlane(hBx, k), rlane(hBy, k))
    #undef QSP_REC
    // lane L now holds gamma_{2L} = (A0r,A0i), gamma_{2L+1} = (A1r,A1i)

    // ---- per-thread prologue: z = e^{2 i theta}, 16 elements ---------------
    const float th16[16] = {t0.x, t0.y, t0.z, t0.w, t1.x, t1.y, t1.z, t1.w,
                            t2.x, t2.y, t2.z, t2.w, t3.x, t3.y, t3.z, t3.w};
    float zr[16], zi[16];
    #pragma unroll
    for (int e = 0; e < 16; ++e) {
        float s, c;
        __sincosf(2.f * th16[e], &s, &c);
        zr[e] = c; zi[e] = s;
    }

    float ar[16], ai[16];
    #pragma unroll
    for (int e = 0; e < 16; ++e) { ar[e] = 0.f; ai[e] = 0.f; }

    // ---- Horner in z, t = 127..0; gamma broadcast via readlane -------------
    #define QSP_STEP(gr, gi)                                                  \
        _Pragma("unroll")                                                     \
        for (int e = 0; e < 16; ++e) {                                        \
            const float nr = fmaf(ar[e], zr[e], fmaf(-ai[e], zi[e], (gr)));   \
            const float ni = fmaf(ar[e], zi[e], fmaf( ai[e], zr[e], (gi)));   \
            ar[e] = nr; ai[e] = ni;                                           \
        }

    #pragma unroll 2
    for (int jj = 63; jj >= 0; --jj) {
        const float g1r = rlane(A1r, jj), g1i = rlane(A1i, jj);
        QSP_STEP(g1r, g1i)               // t = 2jj+1
        const float g0r = rlane(A0r, jj), g0i = rlane(A0i, jj);
        QSP_STEP(g0r, g0i)               // t = 2jj
    }
    #undef QSP_STEP

    // ---- multiply by e^{-127 i theta}: re = ar*C + ai*S, im = ai*C - ar*S --
    float orv[16], oiv[16];
    #pragma unroll
    for (int e = 0; e < 16; ++e) {
        float S, C;
        __sincosf(127.f * th16[e], &S, &C);
        orv[e] = fmaf(ar[e], C,  ai[e] * S);
        oiv[e] = fmaf(ai[e], C, -ar[e] * S);
    }

    if (idx < Bq16) {
        float4* o4 = (float4*)out;
        const int ib = 4 * Bq16;   // imag base in float4 units (= B/4)
        #pragma unroll
        for (int q = 0; q < 4; ++q) {
            o4[4 * idx + q]      = make_float4(orv[4 * q], orv[4 * q + 1],
                                               orv[4 * q + 2], orv[4 * q + 3]);
            o4[ib + 4 * idx + q] = make_float4(oiv[4 * q], oiv[4 * q + 1],
                                               oiv[4 * q + 2], oiv[4 * q + 3]);
        }
    }
}

extern "C" void kernel_launch(void* const* d_in, const int* in_sizes, int n_in,
                              void* d_out, int out_size, void* d_ws, size_t ws_size,
                              hipStream_t stream)
{
    const float* th   = (const float*)d_in[0];
    const float* phis = (const float*)d_in[1];
    float* out = (float*)d_out;
    const int B = in_sizes[0];          // 2097152
    const int Bq16 = B >> 4;            // 131072 threads
    const int block = 256;              // 4 waves
    const int grid = (Bq16 + block - 1) / block;   // 512 blocks = 2/CU, 8 waves/CU
    qsp_fused<<<grid, block, 0, stream>>>(th, phis, out, Bq16);
}

// Round 6
// 90.510 us; speedup vs baseline: 1.1393x; 1.0524x over previous
//
#include <hip/hip_runtime.h>

// QSP via Laurent polynomial, one kernel (R16).
// u00(theta) = sum_t gamma_t e^{i(2t-127)theta}; gamma from phis.
// R14/R15 measured: W=4 waves/SIMD hides latency (69% busy), W=2 does not
// (43%); per-SIMD issue at W=4 was 53% redundant gamma (4 waves x 11.7k cyc).
// R16, at the proven W=4 / E=8 / grid-1024 shape:
//  (1) designated gamma wave per block = blockIdx&3 (spreads across SIMDs
//      for co-resident blocks; avoids R0's all-wave-0 SIMD0 convoy), LDS
//      handoff (1 KiB, one barrier, one ds_read_b128 per lane), Horner still
//      readlane-from-registers.  Gamma issue/SIMD: 46.8k -> 11.7k cyc.
//  (2) packed-FP32 Horner: v_pk_fma_f32 (double-rate on CDNA4; FP32 157 TF
//      = 2x FP64 78.6 TF base). 2 pk-FMA per elem-step via op_sel splats:
//      T   = pk_fma(acc.lo_splat, (zr,zi), (gr,gi))   op_sel:[0,0,0] hi:[0,1,1]
//      acc = pk_fma(acc.hi_splat, (-zi,zr), T)        op_sel:[1,0,0] hi:[1,1,1]

typedef __attribute__((ext_vector_type(2))) float f32x2;

__device__ __forceinline__ float wave_shr1(float x) {
    // lane L <- lane L-1, lane 0 <- 0 (DPP wave_shr:1, bound_ctrl=1)
    return __builtin_bit_cast(float,
        __builtin_amdgcn_update_dpp(0, __builtin_bit_cast(int, x),
                                    0x138, 0xf, 0xf, true));
}

__device__ __forceinline__ float rlane(float x, int l) {
    // broadcast lane l's value to all lanes (l must be wave-uniform)
    return __builtin_bit_cast(float,
        __builtin_amdgcn_readlane(__builtin_bit_cast(int, x), l));
}

__global__ __launch_bounds__(256, 4) void qsp_fused(
    const float* __restrict__ th,
    const float* __restrict__ phis,
    float* __restrict__ out,    // [0,B): real, [B,2B): imag
    int Bq8)                     // B/8
{
    __shared__ float4 gsh[64];   // gamma pairs: lane L -> (g2L.r,g2L.i,g2L1.r,g2L1.i)

    const int tid  = threadIdx.x;
    const int lane = tid & 63;
    const int wv   = tid >> 6;
    const int gwv  = blockIdx.x & 3;   // designated gamma wave for this block
    const int idx  = blockIdx.x * blockDim.x + tid;
    const int lidx = (idx < Bq8) ? idx : 0;

    // issue theta loads first; latency hides under gamma/prologue
    const float4 ta = ((const float4*)th)[2 * lidx];
    const float4 tb = ((const float4*)th)[2 * lidx + 1];

    if (wv == gwv) {
        // ---- gamma recurrence (validated R6-R9/R14), this wave only --------
        float sp, cp;
        __sincosf(phis[lane], &sp, &cp);
        const float hAx = 0.5f * cp, hAy = 0.5f * sp;        // k = lane
        __sincosf(phis[lane + 64], &sp, &cp);
        const float hBx = 0.5f * cp, hBy = 0.5f * sp;        // k = lane + 64

        float A0r = 0.f, A0i = 0.f, B0r = 0.f, B0i = 0.f;
        float A1r = 0.f, A1i = 0.f, B1r = 0.f, B1i = 0.f;
        const float h0x = rlane(hAx, 0), h0y = rlane(hAy, 0);
        if (lane == 0) { A0r = 2.f * h0x; A0i = 2.f * h0y; } // A[0] = e_0

        #define QSP_REC(hx_, hy_)                                             \
        {                                                                     \
            const float hx = (hx_), hy = (hy_);                               \
            const float pAr = wave_shr1(A1r), pAi = wave_shr1(A1i);           \
            const float pBr = wave_shr1(B1r), pBi = wave_shr1(B1i);           \
            const float u0r = pAr + pBr, u0i = pAi + pBi;                     \
            const float v0r = A0r - B0r, v0i = A0i - B0i;                     \
            const float sA0r = u0r + v0r, sA0i = u0i + v0i;                   \
            const float sB0r = u0r - v0r, sB0i = u0i - v0i;                   \
            const float u1r = A0r + B0r, u1i = A0i + B0i;                     \
            const float v1r = A1r - B1r, v1i = A1i - B1i;                     \
            const float sA1r = u1r + v1r, sA1i = u1i + v1i;                   \
            const float sB1r = u1r - v1r, sB1i = u1i - v1i;                   \
            A0r = fmaf(hx, sA0r, -hy * sA0i);                                 \
            A0i = fmaf(hx, sA0i,  hy * sA0r);                                 \
            B0r = fmaf(hx, sB0r,  hy * sB0i);                                 \
            B0i = fmaf(hx, sB0i, -hy * sB0r);                                 \
            A1r = fmaf(hx, sA1r, -hy * sA1i);                                 \
            A1i = fmaf(hx, sA1i,  hy * sA1r);                                 \
            B1r = fmaf(hx, sB1r,  hy * sB1i);                                 \
            B1i = fmaf(hx, sB1i, -hy * sB1r);                                 \
        }
        #pragma unroll 4
        for (int k = 1; k < 64; ++k)   QSP_REC(rlane(hAx, k), rlane(hAy, k))
        #pragma unroll 4
        for (int k = 0; k < 64; ++k)   QSP_REC(rlane(hBx, k), rlane(hBy, k))
        #undef QSP_REC

        gsh[lane] = make_float4(A0r, A0i, A1r, A1i);
    }

    // ---- per-thread prologue (all waves; overlaps gamma wave's recurrence) -
    const float th8[8] = {ta.x, ta.y, ta.z, ta.w, tb.x, tb.y, tb.z, tb.w};
    f32x2 Z[8], W2[8], ACC[8];
    #pragma unroll
    for (int e = 0; e < 8; ++e) {
        float s, c;
        __sincosf(2.f * th8[e], &s, &c);
        Z[e]  = (f32x2){c, s};        // (zr, zi)
        W2[e] = (f32x2){-s, c};       // (-zi, zr)
        ACC[e] = (f32x2){0.f, 0.f};
    }

    __syncthreads();

    // every wave: lane L fetches gamma pair (2L, 2L+1) into registers
    const float4 g = gsh[lane];
    const float G0r = g.x, G0i = g.y, G1r = g.z, G1i = g.w;

    // ---- Horner in z, t = 127..0; packed FP32, gamma via readlane ----------
    // T   = pk_fma(acc.lo, Z, G):  T.lo = ar*zr+gr,   T.hi = ar*zi+gi
    // acc = pk_fma(acc.hi, W2, T): lo = -ai*zi+T.lo,  hi = ai*zr+T.hi
    #define QSP_STEP_PK(Gv)                                                   \
        _Pragma("unroll")                                                     \
        for (int e = 0; e < 8; ++e) {                                         \
            f32x2 T, A2;                                                      \
            asm("v_pk_fma_f32 %0, %1, %2, %3 op_sel:[0,0,0] op_sel_hi:[0,1,1]"\
                : "=v"(T) : "v"(ACC[e]), "v"(Z[e]), "v"(Gv));                 \
            asm("v_pk_fma_f32 %0, %1, %2, %3 op_sel:[1,0,0] op_sel_hi:[1,1,1]"\
                : "=v"(A2) : "v"(ACC[e]), "v"(W2[e]), "v"(T));                \
            ACC[e] = A2;                                                      \
        }

    #pragma unroll 2
    for (int jj = 63; jj >= 0; --jj) {
        const f32x2 Gt1 = {rlane(G1r, jj), rlane(G1i, jj)};
        QSP_STEP_PK(Gt1)                 // t = 2jj+1
        const f32x2 Gt0 = {rlane(G0r, jj), rlane(G0i, jj)};
        QSP_STEP_PK(Gt0)                 // t = 2jj
    }
    #undef QSP_STEP_PK

    // ---- multiply by e^{-127 i theta}: re = ar*C + ai*S, im = ai*C - ar*S --
    float orv[8], oiv[8];
    #pragma unroll
    for (int e = 0; e < 8; ++e) {
        float S, C;
        __sincosf(127.f * th8[e], &S, &C);
        const float arv = ACC[e].x, aiv = ACC[e].y;
        orv[e] = fmaf(arv, C,  aiv * S);
        oiv[e] = fmaf(aiv, C, -arv * S);
    }

    if (idx < Bq8) {
        float4* o4 = (float4*)out;
        const int ib = 2 * Bq8;   // imag base in float4 units (= B/4)
        o4[2 * idx]          = make_float4(orv[0], orv[1], orv[2], orv[3]);
        o4[2 * idx + 1]      = make_float4(orv[4], orv[5], orv[6], orv[7]);
        o4[ib + 2 * idx]     = make_float4(oiv[0], oiv[1], oiv[2], oiv[3]);
        o4[ib + 2 * idx + 1] = make_float4(oiv[4], oiv[5], oiv[6], oiv[7]);
    }
}

extern "C" void kernel_launch(void* const* d_in, const int* in_sizes, int n_in,
                              void* d_out, int out_size, void* d_ws, size_t ws_size,
                              hipStream_t stream)
{
    const float* th   = (const float*)d_in[0];
    const float* phis = (const float*)d_in[1];
    float* out = (float*)d_out;
    const int B = in_sizes[0];          // 2097152
    const int Bq8 = B >> 3;             // 262144 threads
    const int block = 256;              // 4 waves
    const int grid = (Bq8 + block - 1) / block;   // 1024 blocks = 4/CU, 16 waves/CU
    qsp_fused<<<grid, block, 0, stream>>>(th, phis, out, Bq8);
}